// Round 2
// baseline (34.719 us; speedup 1.0000x reference)
//
#include <hip/hip_runtime.h>

#define NROW 256
#define AF   2048
#define BFD  64
#define CFD  32
#define OUTW 2112   // AF + BFD

typedef float          f32x4  __attribute__((ext_vector_type(4)));
typedef short          bf16x8 __attribute__((ext_vector_type(8)));
typedef unsigned short u16x4  __attribute__((ext_vector_type(4)));

static __device__ __forceinline__ unsigned short bft(float x) {
  union { float f; unsigned int u; } v; v.f = x;
  return (unsigned short)(v.u >> 16);   // truncate to bf16 (accuracy irrelevant here)
}

// ---------------------------------------------------------------------------
// Kernel 1: M = f @ T (bf16 MFMA, fp32 accum), M written into out's f-columns
// (row stride OUTW). BM=64, BN=32, BK=64. grid (64 nblk, 4 mblk), 256 thr.
// ---------------------------------------------------------------------------
__global__ __launch_bounds__(256) void gemm_m(const float* __restrict__ f,
                                              const float* __restrict__ T,
                                              float* outM) {
  __shared__ alignas(16) unsigned short Alds[64 * 64];  // [row][k] bf16, byte ^ ((row&7)<<4)
  __shared__ alignas(16) unsigned short Blds[32 * 64];  // [col][k] bf16, byte ^ ((col&7)<<4)

  const int t    = threadIdx.x;
  const int n0   = blockIdx.x * 32;
  const int m0   = blockIdx.y * 64;
  const int lane = t & 63, wave = t >> 6;
  const int wr   = wave >> 1, wc = wave & 1;

  const int bCol = t & 31, bKq = t >> 5;   // B staging: col 0..31, k-octet 0..7

  f32x4 aReg[4];
  float bReg[8];

  // prefetch step 0
#pragma unroll
  for (int it = 0; it < 4; ++it) {
    int s = t + 256 * it, row = s >> 4, kq = s & 15;
    aReg[it] = *(const f32x4*)(f + (m0 + row) * AF + kq * 4);
  }
#pragma unroll
  for (int r = 0; r < 8; ++r)
    bReg[r] = T[(bKq * 8 + r) * 2048 + n0 + bCol];

  f32x4 acc0 = {0.f, 0.f, 0.f, 0.f};
  f32x4 acc1 = {0.f, 0.f, 0.f, 0.f};

  for (int step = 0; step < 32; ++step) {
    __syncthreads();  // previous readers done
    // write staged regs -> LDS (fp32 -> bf16)
#pragma unroll
    for (int it = 0; it < 4; ++it) {
      int s = t + 256 * it, row = s >> 4, kq = s & 15;
      u16x4 u = { bft(aReg[it][0]), bft(aReg[it][1]), bft(aReg[it][2]), bft(aReg[it][3]) };
      *(u16x4*)((char*)Alds + row * 128 + ((kq * 8) ^ ((row & 7) << 4))) = u;
    }
    {
      u16x4 u0 = { bft(bReg[0]), bft(bReg[1]), bft(bReg[2]), bft(bReg[3]) };
      u16x4 u1 = { bft(bReg[4]), bft(bReg[5]), bft(bReg[6]), bft(bReg[7]) };
      int base = bCol * 128, swz = (bCol & 7) << 4;
      *(u16x4*)((char*)Blds + base + ((bKq * 16 + 0) ^ swz)) = u0;
      *(u16x4*)((char*)Blds + base + ((bKq * 16 + 8) ^ swz)) = u1;
    }
    __syncthreads();  // tile ready
    // prefetch next step (overlaps with MFMA below)
    if (step < 31) {
      int k0 = (step + 1) * 64;
#pragma unroll
      for (int it = 0; it < 4; ++it) {
        int s = t + 256 * it, row = s >> 4, kq = s & 15;
        aReg[it] = *(const f32x4*)(f + (m0 + row) * AF + k0 + kq * 4);
      }
#pragma unroll
      for (int r = 0; r < 8; ++r)
        bReg[r] = T[(k0 + bKq * 8 + r) * 2048 + n0 + bCol];
    }
    // compute: wave tile 32x16 = 2 frags, 2 K-slices of 32
#pragma unroll
    for (int kk = 0; kk < 2; ++kk) {
      int kb = kk * 64 + ((lane >> 4) << 4);      // byte offset of lane's k-octet
      int r0 = wr * 32 + (lane & 15);
      int r1 = r0 + 16;
      bf16x8 a0 = *(const bf16x8*)((const char*)Alds + r0 * 128 + (kb ^ ((r0 & 7) << 4)));
      bf16x8 a1 = *(const bf16x8*)((const char*)Alds + r1 * 128 + (kb ^ ((r1 & 7) << 4)));
      int cB = wc * 16 + (lane & 15);
      bf16x8 bb = *(const bf16x8*)((const char*)Blds + cB * 128 + (kb ^ ((cB & 7) << 4)));
      acc0 = __builtin_amdgcn_mfma_f32_16x16x32_bf16(a0, bb, acc0, 0, 0, 0);
      acc1 = __builtin_amdgcn_mfma_f32_16x16x32_bf16(a1, bb, acc1, 0, 0, 0);
    }
  }
  // epilogue: C/D layout col = lane&15, row = (lane>>4)*4 + reg
  const int col = n0 + wc * 16 + (lane & 15);
  const int rb  = m0 + wr * 32 + ((lane >> 4) << 2);
#pragma unroll
  for (int r = 0; r < 4; ++r) {
    outM[(rb + r) * OUTW + col]      = acc0[r];
    outM[(rb + 16 + r) * OUTW + col] = acc1[r];
  }
}

// ---------------------------------------------------------------------------
// Kernel 2: o[j,b] = sum_i exp(-sum_c |M[i,b,c]-M[j,b,c]|)
// grid (b=64, jsplit=8), 256 thr. M read from out's f-columns, o written to
// out's last 64 columns. Per thread: 4 j's x (2 cells of 4 i's) = 32 pairs.
// ---------------------------------------------------------------------------
__global__ __launch_bounds__(256) void pairwise(const float* fM, float* out) {
  __shared__ alignas(16) float Ml[CFD][260];  // [c][i], pad 260 for conflict-free writes
  __shared__ float red[32][33];

  const int b  = blockIdx.x;
  const int js = blockIdx.y;
  const int t  = threadIdx.x;

  // stage M[:, b, :] transposed into LDS
#pragma unroll
  for (int it = 0; it < 8; ++it) {
    int i = it * 32 + (t >> 3), c0 = (t & 7) * 4;
    f32x4 v = *(const f32x4*)(fM + i * OUTW + b * CFD + c0);
    Ml[c0 + 0][i] = v[0]; Ml[c0 + 1][i] = v[1];
    Ml[c0 + 2][i] = v[2]; Ml[c0 + 3][i] = v[3];
  }
  __syncthreads();

  const int jb = t & 7, ir = t >> 3;
  const int j0 = js * 32 + jb * 4;

  f32x4 mjA[16];                       // this thread's 4 j-rows, c = 0..15
#pragma unroll
  for (int c = 0; c < 16; ++c) mjA[c] = *(const f32x4*)&Ml[c][j0];

  float opart[4] = {0.f, 0.f, 0.f, 0.f};

#pragma unroll
  for (int cell = 0; cell < 2; ++cell) {
    const int i0 = (ir + 32 * cell) * 4;
    float acc[4][4];
#pragma unroll
    for (int jj = 0; jj < 4; ++jj)
#pragma unroll
      for (int ii = 0; ii < 4; ++ii) acc[jj][ii] = 0.f;

    // first half: c = 0..15
#pragma unroll
    for (int c = 0; c < 16; ++c) {
      f32x4 mi = *(const f32x4*)&Ml[c][i0];
#pragma unroll
      for (int jj = 0; jj < 4; ++jj)
#pragma unroll
        for (int ii = 0; ii < 4; ++ii)
          acc[jj][ii] += fabsf(mjA[c][jj] - mi[ii]);
    }
    // safe early exit: skipped tail bounded by 256*exp(-30) ~ 2e-11 per output
    float mn = acc[0][0];
#pragma unroll
    for (int jj = 0; jj < 4; ++jj)
#pragma unroll
      for (int ii = 0; ii < 4; ++ii) mn = fminf(mn, acc[jj][ii]);

    if (!__all(mn > 30.0f)) {
#pragma unroll
      for (int c = 16; c < 32; ++c) {
        f32x4 mj = *(const f32x4*)&Ml[c][j0];
        f32x4 mi = *(const f32x4*)&Ml[c][i0];
#pragma unroll
        for (int jj = 0; jj < 4; ++jj)
#pragma unroll
          for (int ii = 0; ii < 4; ++ii)
            acc[jj][ii] += fabsf(mj[jj] - mi[ii]);
      }
    }
#pragma unroll
    for (int jj = 0; jj < 4; ++jj)
#pragma unroll
      for (int ii = 0; ii < 4; ++ii)
        opart[jj] += __expf(-acc[jj][ii]);
  }

  // reduce the 32 ir-partials per j
#pragma unroll
  for (int jj = 0; jj < 4; ++jj) red[ir][jb * 4 + jj] = opart[jj];
  __syncthreads();
  if (t < 32) {
    float s = 0.f;
#pragma unroll
    for (int r = 0; r < 32; ++r) s += red[r][t];
    out[(js * 32 + t) * OUTW + AF + b] = s;
  }
}

// ---------------------------------------------------------------------------
// Kernel 3: copy f into out's first 2048 columns (overwrites the M scratch)
// ---------------------------------------------------------------------------
__global__ __launch_bounds__(256) void copy_f(const float* __restrict__ f,
                                              float* __restrict__ out) {
  int idx = blockIdx.x * 256 + threadIdx.x;   // 0..131071 float4 slots
  int row = idx >> 9, c4 = (idx & 511) * 4;
  *(f32x4*)(out + row * OUTW + c4) = *(const f32x4*)(f + row * AF + c4);
}

extern "C" void kernel_launch(void* const* d_in, const int* in_sizes, int n_in,
                              void* d_out, int out_size, void* d_ws, size_t ws_size,
                              hipStream_t stream) {
  const float* f = (const float*)d_in[0];
  const float* T = (const float*)d_in[1];
  float* out = (float*)d_out;

  gemm_m  <<<dim3(64, 4), 256, 0, stream>>>(f, T, out);   // M -> out f-columns
  pairwise<<<dim3(64, 8), 256, 0, stream>>>(out, out);    // o -> out last cols
  copy_f  <<<512,         256, 0, stream>>>(f, out);      // f over the scratch
}

// Round 3
// 27.985 us; speedup vs baseline: 1.2406x; 1.2406x over previous
//
#include <hip/hip_runtime.h>

#define OUTW 2112   // 2048 + 64

typedef float          f32x4  __attribute__((ext_vector_type(4)));
typedef short          bf16x8 __attribute__((ext_vector_type(8)));
typedef unsigned short u16x4  __attribute__((ext_vector_type(4)));
typedef unsigned short u16x8  __attribute__((ext_vector_type(8)));

static __device__ __forceinline__ unsigned short bft(float x) {
  union { float f; unsigned int u; } v; v.f = x;
  return (unsigned short)(v.u >> 16);   // truncate to bf16; cross-terms underflow anyway
}

static __device__ __forceinline__ void gload_lds16(const void* g, void* l) {
  __builtin_amdgcn_global_load_lds(
      (const __attribute__((address_space(1))) unsigned int*)g,
      (__attribute__((address_space(3))) unsigned int*)l, 16, 0, 0);
}

// ---------------------------------------------------------------------------
// Kernel 1: convert. blocks 0..1023: T (fp32 [k][n]) -> Tt (bf16 [n][k]) via
// LDS 64x64 transpose tiles. blocks 1024..1055: f -> f16 (bf16) + f -> out.
// ---------------------------------------------------------------------------
__global__ __launch_bounds__(256) void convert_k(const float* __restrict__ T,
                                                 const float* __restrict__ f,
                                                 unsigned short* __restrict__ Tt,
                                                 unsigned short* __restrict__ f16,
                                                 float* __restrict__ out) {
  const int bid = blockIdx.x, t = threadIdx.x;
  if (bid < 1024) {
    __shared__ alignas(16) unsigned short tile[64][72];  // pad 72: 144B rows, 16B-aligned
    const int kt = (bid >> 5) * 64, nt = (bid & 31) * 64;
    const int c16 = t & 15, r = t >> 4;
#pragma unroll
    for (int i = 0; i < 4; ++i) {
      int kr = r + 16 * i;
      f32x4 v = *(const f32x4*)(T + (kt + kr) * 2048 + nt + c16 * 4);
#pragma unroll
      for (int e = 0; e < 4; ++e) tile[c16 * 4 + e][kr] = bft(v[e]);
    }
    __syncthreads();
#pragma unroll
    for (int i = 0; i < 2; ++i) {
      int cid = t + 256 * i;                  // 0..511 16B chunks
      int nl = cid >> 3, c = cid & 7;
      u16x8 v = *(const u16x8*)&tile[nl][c * 8];
      *(u16x8*)(Tt + (nt + nl) * 2048 + kt + c * 8) = v;
    }
  } else {
    const int fid = (bid - 1024) * 256 + t;   // 0..8191
#pragma unroll
    for (int i = 0; i < 16; ++i) {
      int u = fid + 8192 * i;                 // 0..131071 f32x4 units
      int row = u >> 9, c4 = (u & 511) * 4;
      f32x4 v = *(const f32x4*)(f + row * 2048 + c4);
      *(f32x4*)(out + row * OUTW + c4) = v;   // fused f-copy into out
      u16x4 h = { bft(v[0]), bft(v[1]), bft(v[2]), bft(v[3]) };
      *(u16x4*)(f16 + row * 2048 + c4) = h;
    }
  }
}

// ---------------------------------------------------------------------------
// Kernel 2: M = f16 @ Tt^T (both row-major-in-K). BM=64 BN=32 BK=64, 256 WGs.
// global_load_lds (16B) staging, pre-swizzled source, depth-3 pipeline,
// 4 LDS buffers, ONE barrier/step, counted vmcnt (6/3/0).
// ---------------------------------------------------------------------------
__global__ __launch_bounds__(256) void gemm_m(const unsigned short* __restrict__ f16,
                                              const unsigned short* __restrict__ Tt,
                                              float* __restrict__ M) {
  __shared__ alignas(16) unsigned char smem[4][12288];  // per buf: A 8KB | B 4KB

  const int bid = blockIdx.x;
  const int m0 = (bid >> 6) * 64;             // 4 m-blocks (slowest → same-XCD share T cols)
  const int n0 = (bid & 63) * 32;             // 64 n-blocks
  const int t = threadIdx.x, lane = t & 63, w = t >> 6;
  const int wr = w >> 1, wc = w & 1;

  // staging source: LDS slot (row, cs) holds global chunk cg = cs ^ (row&7)
  const int lr = lane >> 3;                   // row-in-8 (== row&7 of target row)
  const int lc = (lane & 7) ^ lr;             // pre-swizzled global 16B-chunk
  const unsigned short* aSrc0 = f16 + (m0 + w * 8 + lr) * 2048 + lc * 8;       // rows 0..31
  const unsigned short* aSrc1 = aSrc0 + 32 * 2048;                              // rows 32..63
  const unsigned short* bSrc  = Tt  + (n0 + w * 8 + lr) * 2048 + lc * 8;       // cols 0..31

#define STAGE(ss) {                                              \
    const int koff = (ss) * 64;                                  \
    unsigned char* base = smem[(ss) & 3];                        \
    gload_lds16(aSrc0 + koff, base + w * 1024);                  \
    gload_lds16(aSrc1 + koff, base + 4096 + w * 1024);           \
    gload_lds16(bSrc  + koff, base + 8192 + w * 1024);           \
  }

  f32x4 acc0 = {0.f, 0.f, 0.f, 0.f};
  f32x4 acc1 = {0.f, 0.f, 0.f, 0.f};

  STAGE(0) STAGE(1) STAGE(2)                   // depth-3 prologue (9 loads in flight)

  const int r0 = wr * 32 + (lane & 15);        // A-frag rows (and +16)
  const int nl = wc * 16 + (lane & 15);        // B-frag col-row in Tt tile
  const int hi = lane >> 4;                    // k-octet select
  const int swA = r0 & 7, swB = nl & 7;

#pragma unroll
  for (int step = 0; step < 32; ++step) {
    if (step == 31)      { asm volatile("s_waitcnt vmcnt(0)" ::: "memory"); }
    else if (step == 30) { asm volatile("s_waitcnt vmcnt(3)" ::: "memory"); }
    else                 { asm volatile("s_waitcnt vmcnt(6)" ::: "memory"); }
    __builtin_amdgcn_s_barrier();
    asm volatile("" ::: "memory");             // no LDS reads hoisted above barrier

    const unsigned char* Ab = smem[step & 3];
#pragma unroll
    for (int kk = 0; kk < 2; ++kk) {
      const int cg = kk * 4 + hi;              // global k-chunk 0..7
      bf16x8 a0 = *(const bf16x8*)(Ab + r0 * 128        + ((cg ^ swA) << 4));
      bf16x8 a1 = *(const bf16x8*)(Ab + (r0 + 16) * 128 + ((cg ^ swA) << 4));
      bf16x8 bb = *(const bf16x8*)(Ab + 8192 + nl * 128 + ((cg ^ swB) << 4));
      acc0 = __builtin_amdgcn_mfma_f32_16x16x32_bf16(a0, bb, acc0, 0, 0, 0);
      acc1 = __builtin_amdgcn_mfma_f32_16x16x32_bf16(a1, bb, acc1, 0, 0, 0);
    }
    if (step < 29) STAGE(step + 3)             // write buf[(step-1)&3]: all readers past barrier
  }
#undef STAGE

  // C/D layout: col = lane&15, row = (lane>>4)*4 + reg  (verified R2)
  const int col = n0 + wc * 16 + (lane & 15);
  const int rb  = m0 + wr * 32 + (hi << 2);
#pragma unroll
  for (int r = 0; r < 4; ++r) {
    M[(rb + r) * 2048 + col]      = acc0[r];
    M[(rb + 16 + r) * 2048 + col] = acc1[r];
  }
}

// ---------------------------------------------------------------------------
// Kernel 3: o[j,b] = sum_i exp(-sum_c |M[i,b,c]-M[j,b,c]|)   (unchanged logic,
// M now in d_ws with row stride 2048)
// ---------------------------------------------------------------------------
__global__ __launch_bounds__(256) void pairwise(const float* __restrict__ Mws,
                                                float* __restrict__ out) {
  __shared__ alignas(16) float Ml[32][260];
  __shared__ float red[32][33];

  const int b  = blockIdx.x;
  const int js = blockIdx.y;
  const int t  = threadIdx.x;

#pragma unroll
  for (int it = 0; it < 8; ++it) {
    int i = it * 32 + (t >> 3), c0 = (t & 7) * 4;
    f32x4 v = *(const f32x4*)(Mws + i * 2048 + b * 32 + c0);
    Ml[c0 + 0][i] = v[0]; Ml[c0 + 1][i] = v[1];
    Ml[c0 + 2][i] = v[2]; Ml[c0 + 3][i] = v[3];
  }
  __syncthreads();

  const int jb = t & 7, ir = t >> 3;
  const int j0 = js * 32 + jb * 4;

  f32x4 mjA[16];
#pragma unroll
  for (int c = 0; c < 16; ++c) mjA[c] = *(const f32x4*)&Ml[c][j0];

  float opart[4] = {0.f, 0.f, 0.f, 0.f};

#pragma unroll
  for (int cell = 0; cell < 2; ++cell) {
    const int i0 = (ir + 32 * cell) * 4;
    float acc[4][4];
#pragma unroll
    for (int jj = 0; jj < 4; ++jj)
#pragma unroll
      for (int ii = 0; ii < 4; ++ii) acc[jj][ii] = 0.f;

#pragma unroll
    for (int c = 0; c < 16; ++c) {
      f32x4 mi = *(const f32x4*)&Ml[c][i0];
#pragma unroll
      for (int jj = 0; jj < 4; ++jj)
#pragma unroll
        for (int ii = 0; ii < 4; ++ii)
          acc[jj][ii] += fabsf(mjA[c][jj] - mi[ii]);
    }
    float mn = acc[0][0];
#pragma unroll
    for (int jj = 0; jj < 4; ++jj)
#pragma unroll
      for (int ii = 0; ii < 4; ++ii) mn = fminf(mn, acc[jj][ii]);

    if (!__all(mn > 30.0f)) {                  // tail bound: 256*e^-30 ~ 2e-11
#pragma unroll
      for (int c = 16; c < 32; ++c) {
        f32x4 mj = *(const f32x4*)&Ml[c][j0];
        f32x4 mi = *(const f32x4*)&Ml[c][i0];
#pragma unroll
        for (int jj = 0; jj < 4; ++jj)
#pragma unroll
          for (int ii = 0; ii < 4; ++ii)
            acc[jj][ii] += fabsf(mj[jj] - mi[ii]);
      }
    }
#pragma unroll
    for (int jj = 0; jj < 4; ++jj)
#pragma unroll
      for (int ii = 0; ii < 4; ++ii)
        opart[jj] += __expf(-acc[jj][ii]);
  }

#pragma unroll
  for (int jj = 0; jj < 4; ++jj) red[ir][jb * 4 + jj] = opart[jj];
  __syncthreads();
  if (t < 32) {
    float s = 0.f;
#pragma unroll
    for (int r = 0; r < 32; ++r) s += red[r][t];
    out[(js * 32 + t) * OUTW + 2048 + b] = s;
  }
}

extern "C" void kernel_launch(void* const* d_in, const int* in_sizes, int n_in,
                              void* d_out, int out_size, void* d_ws, size_t ws_size,
                              hipStream_t stream) {
  const float* f = (const float*)d_in[0];
  const float* T = (const float*)d_in[1];
  float* out = (float*)d_out;

  unsigned short* Tt  = (unsigned short*)d_ws;                       // 8 MiB
  unsigned short* f16 = (unsigned short*)((char*)d_ws + 8388608);    // 1 MiB
  float*          M   = (float*)((char*)d_ws + 9437184);             // 2 MiB

  convert_k<<<1056,        256, 0, stream>>>(T, f, Tt, f16, out);
  gemm_m   <<<256,         256, 0, stream>>>(f16, Tt, M);
  pairwise <<<dim3(64, 8), 256, 0, stream>>>(M, out);
}

// Round 4
// 27.751 us; speedup vs baseline: 1.2511x; 1.0084x over previous
//
#include <hip/hip_runtime.h>

#define OUTW 2112   // 2048 + 64

typedef float          f32x4  __attribute__((ext_vector_type(4)));
typedef short          bf16x8 __attribute__((ext_vector_type(8)));
typedef unsigned short u16x4  __attribute__((ext_vector_type(4)));
typedef unsigned short u16x8  __attribute__((ext_vector_type(8)));

static __device__ __forceinline__ unsigned short bft(float x) {
  union { float f; unsigned int u; } v; v.f = x;
  return (unsigned short)(v.u >> 16);   // truncate to bf16; cross-terms underflow anyway
}

static __device__ __forceinline__ void gload_lds16(const void* g, void* l) {
  __builtin_amdgcn_global_load_lds(
      (const __attribute__((address_space(1))) unsigned int*)g,
      (__attribute__((address_space(3))) unsigned int*)l, 16, 0, 0);
}

// ---------------------------------------------------------------------------
// Kernel 1: convert. blocks 0..1023: T (fp32 [k][n]) -> Tt (bf16 [n][k]) via
// LDS 64x64 transpose tiles. blocks 1024..1055: f -> f16 (bf16) + f -> out.
// ---------------------------------------------------------------------------
__global__ __launch_bounds__(256) void convert_k(const float* __restrict__ T,
                                                 const float* __restrict__ f,
                                                 unsigned short* __restrict__ Tt,
                                                 unsigned short* __restrict__ f16,
                                                 float* __restrict__ out) {
  const int bid = blockIdx.x, t = threadIdx.x;
  if (bid < 1024) {
    __shared__ alignas(16) unsigned short tile[64][72];  // pad 72: 144B rows, 16B-aligned
    const int kt = (bid >> 5) * 64, nt = (bid & 31) * 64;
    const int c16 = t & 15, r = t >> 4;
#pragma unroll
    for (int i = 0; i < 4; ++i) {
      int kr = r + 16 * i;
      f32x4 v = *(const f32x4*)(T + (kt + kr) * 2048 + nt + c16 * 4);
#pragma unroll
      for (int e = 0; e < 4; ++e) tile[c16 * 4 + e][kr] = bft(v[e]);
    }
    __syncthreads();
#pragma unroll
    for (int i = 0; i < 2; ++i) {
      int cid = t + 256 * i;                  // 0..511 16B chunks
      int nl = cid >> 3, c = cid & 7;
      u16x8 v = *(const u16x8*)&tile[nl][c * 8];
      *(u16x8*)(Tt + (nt + nl) * 2048 + kt + c * 8) = v;
    }
  } else {
    const int fid = (bid - 1024) * 256 + t;   // 0..8191
#pragma unroll
    for (int i = 0; i < 16; ++i) {
      int u = fid + 8192 * i;                 // 0..131071 f32x4 units
      int row = u >> 9, c4 = (u & 511) * 4;
      f32x4 v = *(const f32x4*)(f + row * 2048 + c4);
      *(f32x4*)(out + row * OUTW + c4) = v;   // fused f-copy into out
      u16x4 h = { bft(v[0]), bft(v[1]), bft(v[2]), bft(v[3]) };
      *(u16x4*)(f16 + row * 2048 + c4) = h;
    }
  }
}

// ---------------------------------------------------------------------------
// Kernel 2: M = f16 @ Tt^T, K-split x2 -> two partials. BM=64 BN=32 BK=128,
// 8 steps, 512 WGs (2/CU for TLP), 3 LDS bufs (72KB), 1 barrier/step,
// counted vmcnt(6), 4 independent acc chains. Both-sides XOR swizzle.
// ---------------------------------------------------------------------------
__global__ __launch_bounds__(256, 2) void gemm_m(const unsigned short* __restrict__ f16,
                                                 const unsigned short* __restrict__ Tt,
                                                 float* __restrict__ M) {
  __shared__ alignas(16) unsigned char smem[3][24576];  // per buf: A 16KB | B 8KB

  const int bid = blockIdx.x;
  const int ksp = bid >> 8;                    // k-split half
  const int rr  = bid & 255;
  const int m0  = (rr >> 6) * 64;              // 4 m-blocks
  const int n0  = (rr & 63) * 32;              // 64 n-blocks (fastest -> XCD by n%8)
  const int t = threadIdx.x, lane = t & 63, w = t >> 6;
  const int wr = w >> 1, wc = w & 1;
  const int k0 = ksp * 1024;

  // staging sources: wave-load j = w*6+i covers 4 rows; LDS dest j*1024 (uniform),
  // HW scatters lane*16. Source pre-swizzled: lane loads global chunk cs^(row&7).
  const unsigned short* src[6];
#pragma unroll
  for (int i = 0; i < 6; ++i) {
    const int j = w * 6 + i;
    const int rowl = lane >> 4, cs = lane & 15;
    int row; const unsigned short* base;
    if (j < 16) { row = j * 4 + rowl;        base = f16 + (m0 + row) * 2048; }
    else        { row = (j - 16) * 4 + rowl; base = Tt  + (n0 + row) * 2048; }
    src[i] = base + k0 + (cs ^ (row & 7)) * 8;
  }

#define STAGE(ss) {                                                     \
    unsigned char* bufp = smem[(ss) % 3];                               \
    _Pragma("unroll")                                                   \
    for (int i = 0; i < 6; ++i)                                         \
      gload_lds16(src[i] + (ss) * 128, bufp + (w * 6 + i) * 1024);      \
  }

  f32x4 acc[2][2];
#pragma unroll
  for (int a = 0; a < 2; ++a)
#pragma unroll
    for (int b = 0; b < 2; ++b) acc[a][b] = f32x4{0.f, 0.f, 0.f, 0.f};

  STAGE(0) STAGE(1)                            // depth-2 prologue (12 loads in flight)

  const int r0 = wr * 32 + (lane & 15);        // A rows r0, r0+16 ((r0+16)&7 == r0&7)
  const int nl = wc * 16 + (lane & 15);        // B row (n within tile)
  const int hi = lane >> 4;
  const int swA = (r0 & 7) << 4, swB = (nl & 7) << 4;

#pragma unroll
  for (int step = 0; step < 8; ++step) {
    if (step == 7) { asm volatile("s_waitcnt vmcnt(0)" ::: "memory"); }
    else           { asm volatile("s_waitcnt vmcnt(6)" ::: "memory"); }
    __builtin_amdgcn_s_barrier();
    asm volatile("" ::: "memory");             // pin LDS reads below barrier

    const unsigned char* Ab = smem[step % 3];
#pragma unroll
    for (int kk = 0; kk < 4; ++kk) {
      const int cgk = (kk * 4 + hi) << 4;      // k-chunk byte offset 0..240
      bf16x8 a0 = *(const bf16x8*)(Ab + r0 * 256        + (cgk ^ swA));
      bf16x8 a1 = *(const bf16x8*)(Ab + (r0 + 16) * 256 + (cgk ^ swA));
      bf16x8 bb = *(const bf16x8*)(Ab + 16384 + nl * 256 + (cgk ^ swB));
      acc[0][kk & 1] = __builtin_amdgcn_mfma_f32_16x16x32_bf16(a0, bb, acc[0][kk & 1], 0, 0, 0);
      acc[1][kk & 1] = __builtin_amdgcn_mfma_f32_16x16x32_bf16(a1, bb, acc[1][kk & 1], 0, 0, 0);
    }
    if (step < 6) STAGE(step + 2)              // buf (step+2)%3 == (step-1)%3: free past barrier
  }
#undef STAGE

  // C/D layout: col = lane&15, row = (lane>>4)*4 + reg
  float* Mp = M + ksp * (256 * 2048);
  const int col = n0 + wc * 16 + (lane & 15);
  const int rb  = m0 + wr * 32 + hi * 4;
  f32x4 o0 = acc[0][0] + acc[0][1];
  f32x4 o1 = acc[1][0] + acc[1][1];
#pragma unroll
  for (int r = 0; r < 4; ++r) {
    Mp[(rb + r) * 2048 + col]      = o0[r];
    Mp[(rb + 16 + r) * 2048 + col] = o1[r];
  }
}

// ---------------------------------------------------------------------------
// Kernel 3: o[j,b] = sum_i exp(-sum_c |M[i,b,c]-M[j,b,c]|). Merges the two
// K-split partials during LDS staging.
// ---------------------------------------------------------------------------
__global__ __launch_bounds__(256) void pairwise(const float* __restrict__ Mws,
                                                float* __restrict__ out) {
  __shared__ alignas(16) float Ml[32][260];
  __shared__ float red[32][33];

  const int b  = blockIdx.x;
  const int js = blockIdx.y;
  const int t  = threadIdx.x;

#pragma unroll
  for (int it = 0; it < 8; ++it) {
    int i = it * 32 + (t >> 3), c0 = (t & 7) * 4;
    f32x4 v0 = *(const f32x4*)(Mws + i * 2048 + b * 32 + c0);
    f32x4 v1 = *(const f32x4*)(Mws + 524288 + i * 2048 + b * 32 + c0);
    f32x4 v = v0 + v1;
    Ml[c0 + 0][i] = v[0]; Ml[c0 + 1][i] = v[1];
    Ml[c0 + 2][i] = v[2]; Ml[c0 + 3][i] = v[3];
  }
  __syncthreads();

  const int jb = t & 7, ir = t >> 3;
  const int j0 = js * 32 + jb * 4;

  f32x4 mjA[16];
#pragma unroll
  for (int c = 0; c < 16; ++c) mjA[c] = *(const f32x4*)&Ml[c][j0];

  float opart[4] = {0.f, 0.f, 0.f, 0.f};

#pragma unroll
  for (int cell = 0; cell < 2; ++cell) {
    const int i0 = (ir + 32 * cell) * 4;
    float acc[4][4];
#pragma unroll
    for (int jj = 0; jj < 4; ++jj)
#pragma unroll
      for (int ii = 0; ii < 4; ++ii) acc[jj][ii] = 0.f;

#pragma unroll
    for (int c = 0; c < 16; ++c) {
      f32x4 mi = *(const f32x4*)&Ml[c][i0];
#pragma unroll
      for (int jj = 0; jj < 4; ++jj)
#pragma unroll
        for (int ii = 0; ii < 4; ++ii)
          acc[jj][ii] += fabsf(mjA[c][jj] - mi[ii]);
    }
    float mn = acc[0][0];
#pragma unroll
    for (int jj = 0; jj < 4; ++jj)
#pragma unroll
      for (int ii = 0; ii < 4; ++ii) mn = fminf(mn, acc[jj][ii]);

    if (!__all(mn > 30.0f)) {                  // tail bound: 256*e^-30 ~ 2e-11
#pragma unroll
      for (int c = 16; c < 32; ++c) {
        f32x4 mj = *(const f32x4*)&Ml[c][j0];
        f32x4 mi = *(const f32x4*)&Ml[c][i0];
#pragma unroll
        for (int jj = 0; jj < 4; ++jj)
#pragma unroll
          for (int ii = 0; ii < 4; ++ii)
            acc[jj][ii] += fabsf(mj[jj] - mi[ii]);
      }
    }
#pragma unroll
    for (int jj = 0; jj < 4; ++jj)
#pragma unroll
      for (int ii = 0; ii < 4; ++ii)
        opart[jj] += __expf(-acc[jj][ii]);
  }

#pragma unroll
  for (int jj = 0; jj < 4; ++jj) red[ir][jb * 4 + jj] = opart[jj];
  __syncthreads();
  if (t < 32) {
    float s = 0.f;
#pragma unroll
    for (int r = 0; r < 32; ++r) s += red[r][t];
    out[(js * 32 + t) * OUTW + 2048 + b] = s;
  }
}

extern "C" void kernel_launch(void* const* d_in, const int* in_sizes, int n_in,
                              void* d_out, int out_size, void* d_ws, size_t ws_size,
                              hipStream_t stream) {
  const float* f = (const float*)d_in[0];
  const float* T = (const float*)d_in[1];
  float* out = (float*)d_out;

  unsigned short* Tt  = (unsigned short*)d_ws;                       // 8 MiB
  unsigned short* f16 = (unsigned short*)((char*)d_ws + 8388608);    // 1 MiB
  float*          M   = (float*)((char*)d_ws + 9437184);             // 2 x 2 MiB partials

  convert_k<<<1056,        256, 0, stream>>>(T, f, Tt, f16, out);
  gemm_m   <<<512,         256, 0, stream>>>(f16, Tt, M);
  pairwise <<<dim3(64, 8), 256, 0, stream>>>(M, out);
}

// Round 5
// 26.084 us; speedup vs baseline: 1.3311x; 1.0639x over previous
//
#include <hip/hip_runtime.h>

#define OUTW 2112   // 2048 + 64

typedef float          f32x4  __attribute__((ext_vector_type(4)));
typedef short          bf16x8 __attribute__((ext_vector_type(8)));
typedef unsigned short u16x8  __attribute__((ext_vector_type(8)));

static __device__ __forceinline__ unsigned short bft(float x) {
  union { float f; unsigned int u; } v; v.f = x;
  return (unsigned short)(v.u >> 16);   // truncate to bf16 (error provably inert here)
}

// raw barrier: drain LDS ops but keep global prefetch loads in flight (avoid
// __syncthreads' vmcnt(0) drain — the m97 stall)
#define BAR() { asm volatile("s_waitcnt lgkmcnt(0)" ::: "memory");  \
                __builtin_amdgcn_s_barrier();                        \
                __builtin_amdgcn_sched_barrier(0); }

// ---------------------------------------------------------------------------
// Kernel 1: fused convert + GEMM.  Mb(bf16 256x2048) = bf16(f) @ bf16(T).
// grid 256 (4 m-blocks x 64 n-blocks), 512 thr (8 waves, 16x16 tile each).
// BM=64 BN=32 BK=128, 16 steps. Reg-stage fp32 -> cvt -> swizzled ds_write.
// B-operand transposed during staging via k-gather (coalesced over n).
// ---------------------------------------------------------------------------
__global__ __launch_bounds__(512) void gemm_f(const float* __restrict__ f,
                                              const float* __restrict__ T,
                                              unsigned short* __restrict__ Mb) {
  __shared__ alignas(16) unsigned char smem[2][24576];  // per buf: A 16KB | B 8KB

  const int bid = blockIdx.x;
  const int m0 = (bid >> 6) * 64;
  const int n0 = (bid & 63) * 32;     // 4 m-blocks of same n0 are bid±64k -> same XCD (L2 share)
  const int t = threadIdx.x, lane = t & 63, w = t >> 6;

  // A staging slots (row, 16B-chunk): s = t and t+512
  const int ar0 = t >> 4;             // rows 0..31
  const int ar1 = ar0 + 32;           // rows 32..63
  const int ac  = t & 15;             // chunk 0..15 (8 fp32 -> 8 bf16)
  // B staging slot: n-row gather of one k-octet
  const int bn  = t & 31, bko = t >> 5;   // n 0..31, k-octet 0..15

  const float* fA0 = f + (m0 + ar0) * 2048 + ac * 8;
  const float* fA1 = f + (m0 + ar1) * 2048 + ac * 8;
  const float* fB  = T + bko * 8 * 2048 + n0 + bn;

  f32x4 rA[4];
  float rB[8];

#define LOADS(st) {                                                        \
    const int k0 = (st) * 128;                                             \
    rA[0] = *(const f32x4*)(fA0 + k0);  rA[1] = *(const f32x4*)(fA0 + k0 + 4); \
    rA[2] = *(const f32x4*)(fA1 + k0);  rA[3] = *(const f32x4*)(fA1 + k0 + 4); \
    _Pragma("unroll")                                                      \
    for (int j = 0; j < 8; ++j) rB[j] = fB[(k0 + j) * 2048];               \
  }

#define PACKWRITE(bsel) {                                                  \
    unsigned char* Ab = smem[bsel];                                        \
    u16x8 pa0 = { bft(rA[0][0]), bft(rA[0][1]), bft(rA[0][2]), bft(rA[0][3]), \
                  bft(rA[1][0]), bft(rA[1][1]), bft(rA[1][2]), bft(rA[1][3]) }; \
    u16x8 pa1 = { bft(rA[2][0]), bft(rA[2][1]), bft(rA[2][2]), bft(rA[2][3]), \
                  bft(rA[3][0]), bft(rA[3][1]), bft(rA[3][2]), bft(rA[3][3]) }; \
    u16x8 pb  = { bft(rB[0]), bft(rB[1]), bft(rB[2]), bft(rB[3]),          \
                  bft(rB[4]), bft(rB[5]), bft(rB[6]), bft(rB[7]) };        \
    *(u16x8*)(Ab + ar0 * 256 + ((ac ^ (ar0 & 7)) << 4)) = pa0;             \
    *(u16x8*)(Ab + ar1 * 256 + ((ac ^ (ar1 & 7)) << 4)) = pa1;             \
    *(u16x8*)(Ab + 16384 + bn * 256 + ((bko ^ (bn & 7)) << 4)) = pb;       \
  }

  // MFMA fragment addressing (16x16x32, layouts verified R2-R4)
  const int r0 = (w >> 1) * 16 + (lane & 15);   // A row
  const int nl = (w & 1) * 16 + (lane & 15);    // B col-row
  const int hi = lane >> 4;
  const int swA = (r0 & 7) << 4, swB = (nl & 7) << 4;

  f32x4 acc0 = {0.f, 0.f, 0.f, 0.f};
  f32x4 acc1 = {0.f, 0.f, 0.f, 0.f};

  LOADS(0)
#pragma unroll
  for (int step = 0; step < 16; ++step) {
    PACKWRITE(step & 1)                 // compiler inserts exact vmcnt before pack
    if (step < 15) LOADS(step + 1)      // prefetch stays in flight across BAR
    BAR()                               // writes visible; reads of buf done 2 steps ago
    const unsigned char* Ab = smem[step & 1];
#pragma unroll
    for (int kk = 0; kk < 4; ++kk) {
      const int cgk = (kk * 4 + hi) << 4;
      bf16x8 a = *(const bf16x8*)(Ab + r0 * 256 + (cgk ^ swA));
      bf16x8 b = *(const bf16x8*)(Ab + 16384 + nl * 256 + (cgk ^ swB));
      if (kk & 1) acc1 = __builtin_amdgcn_mfma_f32_16x16x32_bf16(a, b, acc1, 0, 0, 0);
      else        acc0 = __builtin_amdgcn_mfma_f32_16x16x32_bf16(a, b, acc0, 0, 0, 0);
    }
  }
#undef LOADS
#undef PACKWRITE

  // C/D layout: col = lane&15, row = (lane>>4)*4 + reg
  f32x4 o = acc0 + acc1;
  const int col = n0 + nl;
  const int rb  = m0 + (w >> 1) * 16 + hi * 4;
#pragma unroll
  for (int r = 0; r < 4; ++r)
    Mb[(rb + r) * 2048 + col] = bft(o[r]);
}

// ---------------------------------------------------------------------------
// Kernel 2: pairwise + fused f->out copy.
// o[j,b] = sum_i exp(-sum_c |M[i,b,c]-M[j,b,c]|), M in bf16.
// grid (b=64, js=8), 256 thr.
// ---------------------------------------------------------------------------
__global__ __launch_bounds__(256) void pairwise(const unsigned short* __restrict__ Mb,
                                                const float* __restrict__ f,
                                                float* __restrict__ out) {
  __shared__ alignas(16) float Ml[32][260];
  __shared__ float red[32][33];

  const int b  = blockIdx.x;
  const int js = blockIdx.y;
  const int t  = threadIdx.x;

  // fused f copy (512 blocks x 256 thr x 16B = 2 MB exactly)
  {
    const int u = (js * 64 + b) * 256 + t;
    const int row = u >> 9, c4 = (u & 511) * 4;
    *(f32x4*)(out + row * OUTW + c4) = *(const f32x4*)(f + row * 2048 + c4);
  }

  // stage M[:, b, :] transposed (bf16 -> f32)
#pragma unroll
  for (int it = 0; it < 4; ++it) {
    const int i = it * 64 + (t >> 2), c0 = (t & 3) * 8;
    u16x8 v = *(const u16x8*)(Mb + i * 2048 + b * 32 + c0);
#pragma unroll
    for (int e = 0; e < 8; ++e) {
      union { unsigned int u; float f; } q;
      q.u = ((unsigned int)(unsigned short)v[e]) << 16;
      Ml[c0 + e][i] = q.f;
    }
  }
  __syncthreads();

  const int jb = t & 7, ir = t >> 3;
  const int j0 = js * 32 + jb * 4;

  f32x4 mjA[16];
#pragma unroll
  for (int c = 0; c < 16; ++c) mjA[c] = *(const f32x4*)&Ml[c][j0];

  float opart[4] = {0.f, 0.f, 0.f, 0.f};

#pragma unroll
  for (int cell = 0; cell < 2; ++cell) {
    const int i0 = (ir + 32 * cell) * 4;
    float acc[4][4];
#pragma unroll
    for (int jj = 0; jj < 4; ++jj)
#pragma unroll
      for (int ii = 0; ii < 4; ++ii) acc[jj][ii] = 0.f;

#pragma unroll
    for (int c = 0; c < 16; ++c) {
      f32x4 mi = *(const f32x4*)&Ml[c][i0];
#pragma unroll
      for (int jj = 0; jj < 4; ++jj)
#pragma unroll
        for (int ii = 0; ii < 4; ++ii)
          acc[jj][ii] += fabsf(mjA[c][jj] - mi[ii]);
    }
    float mn = acc[0][0];
#pragma unroll
    for (int jj = 0; jj < 4; ++jj)
#pragma unroll
      for (int ii = 0; ii < 4; ++ii) mn = fminf(mn, acc[jj][ii]);

    if (!__all(mn > 30.0f)) {            // skipped tail <= 256*e^-30 ~ 2e-11
#pragma unroll
      for (int c = 16; c < 32; ++c) {
        f32x4 mj = *(const f32x4*)&Ml[c][j0];
        f32x4 mi = *(const f32x4*)&Ml[c][i0];
#pragma unroll
        for (int jj = 0; jj < 4; ++jj)
#pragma unroll
          for (int ii = 0; ii < 4; ++ii)
            acc[jj][ii] += fabsf(mj[jj] - mi[ii]);
      }
    }
#pragma unroll
    for (int jj = 0; jj < 4; ++jj)
#pragma unroll
      for (int ii = 0; ii < 4; ++ii)
        opart[jj] += __expf(-acc[jj][ii]);
  }

#pragma unroll
  for (int jj = 0; jj < 4; ++jj) red[ir][jb * 4 + jj] = opart[jj];
  __syncthreads();
  if (t < 32) {
    float s = 0.f;
#pragma unroll
    for (int r = 0; r < 32; ++r) s += red[r][t];
    out[(js * 32 + t) * OUTW + 2048 + b] = s;
  }
}

extern "C" void kernel_launch(void* const* d_in, const int* in_sizes, int n_in,
                              void* d_out, int out_size, void* d_ws, size_t ws_size,
                              hipStream_t stream) {
  const float* f = (const float*)d_in[0];
  const float* T = (const float*)d_in[1];
  float* out = (float*)d_out;

  unsigned short* Mb = (unsigned short*)d_ws;   // 1 MiB bf16 M

  gemm_f  <<<256,         512, 0, stream>>>(f, T, Mb);
  pairwise<<<dim3(64, 8), 256, 0, stream>>>(Mb, f, out);
}